// Round 3
// baseline (469.544 us; speedup 1.0000x reference)
//
#include <hip/hip_runtime.h>

// Round-8: single-pass decoupled-lookback cumulative max, row-contiguous.
// Round-7 post-mortem: two-kernel segment scan reached ~4.1 GB/ms effective
// (vs 2.9 round-5) -> row-contiguous access works, but the second full read
// of x between kernels (through a fill-thrashed L3) ate the gain.
// Harness fill dispatches prove 6.8 TB/s streaming writes are achievable.
// Fix: ONE kernel. Block (b,s) = 32-row segment:
//   phase 1: stream own 128 KB, column-max -> publish aggregate (4 KB) +
//            release-flag (agent scope).
//   phase 2: thread 0 spin-waits (acquire, bounded) on the <=31 predecessor
//            flags; on timeout the block recomputes that aggregate from x
//            directly -> forward progress never depends on dispatch order
//            or co-residency (G16-safe). Carry = max of predecessors.
//   phase 3: re-read own segment (L2-hot: just touched, 32 blocks x 128 KB
//            = 4 MB per XCD) and stream out the scan.
// HBM traffic = minimum: read x once (~128 MB) + write out (~132 MB).
// Flags are zeroed per launch via hipMemsetAsync (graph-capture-safe; the
// harness itself enqueues memsets).

constexpr int B = 32;
constexpr int H = 1024;
constexpr int W = 1024;
constexpr int ROW4 = W / 4;        // 256 float4 per row = 4 KB
constexpr int NSEG = 32;           // segments along H
constexpr int SH = H / NSEG;       // 32 rows per segment
constexpr int NB = B * NSEG;       // 1024 blocks
constexpr size_t AGG_BYTES = (size_t)NB * ROW4 * sizeof(float4);  // 4 MiB
constexpr size_t WS_BYTES = AGG_BYTES + (size_t)NB * sizeof(unsigned);

__device__ __forceinline__ float4 max4(float4 a, float4 b) {
    return make_float4(fmaxf(a.x, b.x), fmaxf(a.y, b.y),
                       fmaxf(a.z, b.z), fmaxf(a.w, b.w));
}

__global__ __launch_bounds__(256) void cummax_lb(const float* __restrict__ xf,
                                                 float* __restrict__ of,
                                                 float4* __restrict__ agg,
                                                 unsigned* __restrict__ flags) {
    const int id = blockIdx.x;
    const int b = id >> 5;             // image
    const int s = id & (NSEG - 1);     // segment along H
    const int t = threadIdx.x;
    const float4* x4 = (const float4*)xf;
    float4* o4 = (float4*)of;
    const size_t base = ((size_t)b * H + (size_t)s * SH) * ROW4 + t;

    const float ninf = -__builtin_inff();
    const float4 ninf4 = make_float4(ninf, ninf, ninf, ninf);

    // ---------------- phase 1: own-segment column max ----------------
    float4 m = ninf4;
#pragma unroll
    for (int g = 0; g < SH; g += 8) {
        float4 v[8];
#pragma unroll
        for (int r = 0; r < 8; ++r) v[r] = x4[base + (size_t)(g + r) * ROW4];
#pragma unroll
        for (int r = 0; r < 8; ++r) m = max4(m, v[r]);
    }
    agg[(size_t)id * ROW4 + t] = m;
    __syncthreads();   // drains vmcnt(0): all 256 threads' agg stores in L2
    if (t == 0)
        __hip_atomic_store(&flags[id], 1u, __ATOMIC_RELEASE,
                           __HIP_MEMORY_SCOPE_AGENT);  // wbL2 + L3 atomic

    // ---------------- phase 2: lookback over predecessors ----------------
    __shared__ unsigned missing_sh;
    if (t == 0) {
        unsigned miss = 0;
        for (int k = 0; k < s; ++k) {
            int tries = 0;
            while (__hip_atomic_load(&flags[(id & ~(NSEG - 1)) | k],
                                     __ATOMIC_ACQUIRE,
                                     __HIP_MEMORY_SCOPE_AGENT) == 0u) {
                if (++tries > (1 << 15)) { miss |= 1u << k; break; }
                __builtin_amdgcn_s_sleep(2);
            }
        }
        missing_sh = miss;
    }
    __syncthreads();
    const unsigned miss = missing_sh;

    float4 carry = ninf4;
    for (int k = 0; k < s; ++k) {
        if ((miss >> k) & 1u) {
            // predecessor never published (non-resident scheduling):
            // recompute its aggregate straight from x. Rare/never path.
            const size_t kb = ((size_t)b * H + (size_t)k * SH) * ROW4 + t;
            float4 a = ninf4;
            for (int r = 0; r < SH; ++r)
                a = max4(a, x4[kb + (size_t)r * ROW4]);
            carry = max4(carry, a);
        } else {
            carry = max4(carry, agg[(size_t)((id & ~(NSEG - 1)) | k) * ROW4 + t]);
        }
    }

    // ---------------- phase 3: re-read own segment (L2-hot), scan, store ----
#pragma unroll
    for (int g = 0; g < SH; g += 8) {
        float4 v[8];
#pragma unroll
        for (int r = 0; r < 8; ++r) v[r] = x4[base + (size_t)(g + r) * ROW4];
#pragma unroll
        for (int r = 0; r < 8; ++r) {
            carry = max4(carry, v[r]);
            o4[base + (size_t)(g + r) * ROW4] = carry;
        }
    }
}

// ---------------- fallback (round-5 verified kernel) if ws too small --------
constexpr int F_SW4 = 8;
constexpr int F_NSTRIP = ROW4 / F_SW4;
constexpr int F_CH = 128;
constexpr int F_NCHUNK = H / F_CH;
constexpr int F_R = 4;

__device__ __forceinline__ float4 shflup4(float4 v, int d) {
    float4 r;
    r.x = __shfl_up(v.x, d, 64);
    r.y = __shfl_up(v.y, d, 64);
    r.z = __shfl_up(v.z, d, 64);
    r.w = __shfl_up(v.w, d, 64);
    return r;
}

__global__ __launch_bounds__(256) void cummax_sp(const float* __restrict__ xf,
                                                 float* __restrict__ of) {
    __shared__ float4 wavetot[2][32];
    const int tid = threadIdx.x;
    const int lane = tid & 63;
    const int wid = tid >> 6;
    const int w = tid & 7;
    const int hsegG = tid >> 3;
    const int hseg_l = (tid >> 3) & 7;
    const int b = blockIdx.x >> 5;
    const int strip = blockIdx.x & (F_NSTRIP - 1);
    const float4* x4 = (const float4*)xf;
    float4* o4 = (float4*)of;
    const size_t tbase = (size_t)b * (H * ROW4) + (size_t)strip * F_SW4 + w;
    const float ninf = -__builtin_inff();
    const float4 ninf4 = make_float4(ninf, ninf, ninf, ninf);
    float4 carry = ninf4;
    float4 cur[F_R], nxt[F_R];
#pragma unroll
    for (int r = 0; r < F_R; ++r)
        cur[r] = x4[tbase + (size_t)(hsegG * F_R + r) * ROW4];
#pragma unroll
    for (int c = 0; c < F_NCHUNK; ++c) {
        if (c + 1 < F_NCHUNK) {
#pragma unroll
            for (int r = 0; r < F_R; ++r)
                nxt[r] = x4[tbase + (size_t)((c + 1) * F_CH + hsegG * F_R + r) * ROW4];
        }
        float4 m = max4(max4(cur[0], cur[1]), max4(cur[2], cur[3]));
        float4 incl = m;
        { float4 t = shflup4(incl, 8);  if (lane >= 8)  incl = max4(incl, t); }
        { float4 t = shflup4(incl, 16); if (lane >= 16) incl = max4(incl, t); }
        { float4 t = shflup4(incl, 32); if (lane >= 32) incl = max4(incl, t); }
        float4 ew = shflup4(incl, 8);
        float4 excl = (hseg_l == 0) ? ninf4 : ew;
        if (hseg_l == 7) wavetot[c & 1][wid * 8 + w] = incl;
        __syncthreads();
        float4 crosspre = carry;
        float4 tot = carry;
#pragma unroll
        for (int w2 = 0; w2 < 4; ++w2) {
            float4 v = wavetot[c & 1][w2 * 8 + w];
            if (w2 < wid) crosspre = max4(crosspre, v);
            tot = max4(tot, v);
        }
        carry = tot;
        float4 a = max4(crosspre, excl);
#pragma unroll
        for (int r = 0; r < F_R; ++r) {
            a = max4(a, cur[r]);
            o4[tbase + (size_t)(c * F_CH + hsegG * F_R + r) * ROW4] = a;
        }
        if (c + 1 < F_NCHUNK) {
#pragma unroll
            for (int r = 0; r < F_R; ++r) cur[r] = nxt[r];
        }
    }
}

extern "C" void kernel_launch(void* const* d_in, const int* in_sizes, int n_in,
                              void* d_out, int out_size, void* d_ws, size_t ws_size,
                              hipStream_t stream) {
    const float* x = (const float*)d_in[0];
    float* out = (float*)d_out;
    if (d_ws != nullptr && ws_size >= WS_BYTES) {
        float4* agg = (float4*)d_ws;
        unsigned* flags = (unsigned*)((char*)d_ws + AGG_BYTES);
        hipMemsetAsync(flags, 0, NB * sizeof(unsigned), stream);
        cummax_lb<<<NB, 256, 0, stream>>>(x, out, agg, flags);
    } else {
        cummax_sp<<<B * F_NSTRIP, 256, 0, stream>>>(x, out);
    }
}

// Round 4
// 375.567 us; speedup vs baseline: 1.2502x; 1.2502x over previous
//
#include <hip/hip_runtime.h>
#include <hip/hip_cooperative_groups.h>

namespace cg = cooperative_groups;

// Round-9: cooperative single-pass segment scan (grid.sync instead of flags).
// Round-8 post-mortem: decoupled lookback hit IDEAL traffic (FETCH 152 MB,
// WRITE 135.2 MB exact) but 320 us @ 0.92 TB/s, VALU 1.3% -> pure waiting.
// Cause: per-block RELEASE store = full L2 writeback (buffer_wbl2), each
// spin ACQUIRE = L2 invalidate; 1024 blocks of that serialized the machine.
// Algorithm was right; the sync primitive was wrong.
// Fix: ONE cooperative grid sync (one wb/inv per XCD total).
//   phase 1: block (b,s) streams its 32-row segment row-contiguously
//            (thread t = float4-column t; 1 KB per wave-instruction),
//            column-max -> agg[id] (4 KB, plain stores).
//   grid.sync()
//   phase 2: predicated lookback over agg[b][k<s] (avg 62 KB, L3).
//   phase 3: re-read own segment (L3-resident; FETCH counts HBM only),
//            running max, row-contiguous stores.
// HBM traffic: x once (~134 MB) + out (~134 MB) + agg 4 MB.
// __launch_bounds__(256,4) caps VGPR at 128 -> 4 blocks/CU -> all 1024
// blocks co-resident (cooperative-launch requirement).

constexpr int B = 32;
constexpr int H = 1024;
constexpr int W = 1024;
constexpr int ROW4 = W / 4;        // 256 float4 per row = 4 KB
constexpr int NSEG = 32;           // segments along H
constexpr int SH = H / NSEG;       // 32 rows per segment
constexpr int NB = B * NSEG;       // 1024 blocks
constexpr size_t AGG_BYTES = (size_t)NB * ROW4 * sizeof(float4);  // 4 MiB

__device__ __forceinline__ float4 max4(float4 a, float4 b) {
    return make_float4(fmaxf(a.x, b.x), fmaxf(a.y, b.y),
                       fmaxf(a.z, b.z), fmaxf(a.w, b.w));
}

__global__ __launch_bounds__(256, 4) void cummax_coop(const float* __restrict__ xf,
                                                      float* __restrict__ of,
                                                      float* __restrict__ aggf) {
    const int id = blockIdx.x;
    const int b = id >> 5;             // image
    const int s = id & (NSEG - 1);     // segment along H
    const int t = threadIdx.x;         // float4-column within the 4 KB row
    const float4* x4 = (const float4*)xf;
    float4* o4 = (float4*)of;
    float4* agg = (float4*)aggf;
    const size_t base = ((size_t)b * H + (size_t)s * SH) * ROW4 + t;

    const float ninf = -__builtin_inff();
    const float4 ninf4 = make_float4(ninf, ninf, ninf, ninf);

    // ---------------- phase 1: own-segment column max ----------------
    float4 m = ninf4;
#pragma unroll
    for (int g = 0; g < SH; g += 8) {
        float4 v[8];
#pragma unroll
        for (int r = 0; r < 8; ++r) v[r] = x4[base + (size_t)(g + r) * ROW4];
#pragma unroll
        for (int r = 0; r < 8; ++r) m = max4(m, v[r]);
    }
    agg[(size_t)id * ROW4 + t] = m;    // plain store; grid.sync publishes it

    // ---------------- one grid-wide sync (device-scope fence) -------------
    cg::this_grid().sync();

    // ---------------- phase 2: bounded predicated lookback ----------------
    float4 carry = ninf4;
    for (int g = 0; g < s; g += 8) {   // g <= 24, g+k <= 31: always in-bounds
        float4 v[8];
#pragma unroll
        for (int k = 0; k < 8; ++k)
            v[k] = agg[(size_t)(b * NSEG + g + k) * ROW4 + t];
#pragma unroll
        for (int k = 0; k < 8; ++k)
            if (g + k < s) carry = max4(carry, v[k]);
    }

    // ---------------- phase 3: re-read own segment, scan, store ----------
#pragma unroll
    for (int g = 0; g < SH; g += 8) {
        float4 v[8];
#pragma unroll
        for (int r = 0; r < 8; ++r) v[r] = x4[base + (size_t)(g + r) * ROW4];
#pragma unroll
        for (int r = 0; r < 8; ++r) {
            carry = max4(carry, v[r]);
            o4[base + (size_t)(g + r) * ROW4] = carry;
        }
    }
}

// ---------------- fallback (round-5 verified kernel) ----------------------
constexpr int F_SW4 = 8;
constexpr int F_NSTRIP = ROW4 / F_SW4;
constexpr int F_CH = 128;
constexpr int F_NCHUNK = H / F_CH;
constexpr int F_R = 4;

__device__ __forceinline__ float4 shflup4(float4 v, int d) {
    float4 r;
    r.x = __shfl_up(v.x, d, 64);
    r.y = __shfl_up(v.y, d, 64);
    r.z = __shfl_up(v.z, d, 64);
    r.w = __shfl_up(v.w, d, 64);
    return r;
}

__global__ __launch_bounds__(256) void cummax_sp(const float* __restrict__ xf,
                                                 float* __restrict__ of) {
    __shared__ float4 wavetot[2][32];
    const int tid = threadIdx.x;
    const int lane = tid & 63;
    const int wid = tid >> 6;
    const int w = tid & 7;
    const int hsegG = tid >> 3;
    const int hseg_l = (tid >> 3) & 7;
    const int b = blockIdx.x >> 5;
    const int strip = blockIdx.x & (F_NSTRIP - 1);
    const float4* x4 = (const float4*)xf;
    float4* o4 = (float4*)of;
    const size_t tbase = (size_t)b * (H * ROW4) + (size_t)strip * F_SW4 + w;
    const float ninf = -__builtin_inff();
    const float4 ninf4 = make_float4(ninf, ninf, ninf, ninf);
    float4 carry = ninf4;
    float4 cur[F_R], nxt[F_R];
#pragma unroll
    for (int r = 0; r < F_R; ++r)
        cur[r] = x4[tbase + (size_t)(hsegG * F_R + r) * ROW4];
#pragma unroll
    for (int c = 0; c < F_NCHUNK; ++c) {
        if (c + 1 < F_NCHUNK) {
#pragma unroll
            for (int r = 0; r < F_R; ++r)
                nxt[r] = x4[tbase + (size_t)((c + 1) * F_CH + hsegG * F_R + r) * ROW4];
        }
        float4 m = max4(max4(cur[0], cur[1]), max4(cur[2], cur[3]));
        float4 incl = m;
        { float4 t = shflup4(incl, 8);  if (lane >= 8)  incl = max4(incl, t); }
        { float4 t = shflup4(incl, 16); if (lane >= 16) incl = max4(incl, t); }
        { float4 t = shflup4(incl, 32); if (lane >= 32) incl = max4(incl, t); }
        float4 ew = shflup4(incl, 8);
        float4 excl = (hseg_l == 0) ? ninf4 : ew;
        if (hseg_l == 7) wavetot[c & 1][wid * 8 + w] = incl;
        __syncthreads();
        float4 crosspre = carry;
        float4 tot = carry;
#pragma unroll
        for (int w2 = 0; w2 < 4; ++w2) {
            float4 v = wavetot[c & 1][w2 * 8 + w];
            if (w2 < wid) crosspre = max4(crosspre, v);
            tot = max4(tot, v);
        }
        carry = tot;
        float4 a = max4(crosspre, excl);
#pragma unroll
        for (int r = 0; r < F_R; ++r) {
            a = max4(a, cur[r]);
            o4[tbase + (size_t)(c * F_CH + hsegG * F_R + r) * ROW4] = a;
        }
        if (c + 1 < F_NCHUNK) {
#pragma unroll
            for (int r = 0; r < F_R; ++r) cur[r] = nxt[r];
        }
    }
}

extern "C" void kernel_launch(void* const* d_in, const int* in_sizes, int n_in,
                              void* d_out, int out_size, void* d_ws, size_t ws_size,
                              hipStream_t stream) {
    const float* x = (const float*)d_in[0];
    float* out = (float*)d_out;
    if (d_ws != nullptr && ws_size >= AGG_BYTES) {
        float* agg = (float*)d_ws;
        void* args[3] = {(void*)&x, (void*)&out, (void*)&agg};
        hipError_t e = hipLaunchCooperativeKernel(
            reinterpret_cast<const void*>(cummax_coop), dim3(NB), dim3(256),
            args, 0, stream);
        if (e == hipSuccess) return;
        (void)hipGetLastError();  // clear error state, fall through
    }
    cummax_sp<<<B * F_NSTRIP, 256, 0, stream>>>(x, out);
}

// Round 6
// 236.174 us; speedup vs baseline: 1.9881x; 1.5902x over previous
//
#include <hip/hip_runtime.h>

// Round-11: round-10 with the OOB bug fixed (D=24 did not divide H=1024 ->
// prefetch read 8 rows past the last image + epilogue wrote rows 1008..1031
// OOB -> core dump). D=32 divides H exactly; coverage and bounds verified:
//   main loop hb=0..960 step 32: processes rows 0..991, prefetches <=1023
//   epilogue: rows 992..1023. No access beyond the image.
// Theory (untested by r10's crash): rounds 5/6 capped at 2.33 TB/s because
// every memory instruction touched 8-16 lines spaced exactly 4 KB apart
// (same channel slice) -> per-instruction serialization. Here each
// instruction's footprint is ONE contiguous 256 B chunk (64 lanes x 1
// float); the 4 KB stride is across instructions, not inside one.
// Wave owns a 256 B x H strip: carry in a register, zero sync, zero LDS,
// x read exactly once, out written exactly once, all full-line accesses.
// buf[32] = 8 KB/wave of reads in flight (static indices), stores are
// fire-and-forget. 512 one-wave blocks = 2 blocks/CU.

constexpr int B = 32;
constexpr int H = 1024;
constexpr int W = 1024;            // floats per row (4 KB)
constexpr int SWF = 64;            // strip width in floats = 256 B
constexpr int NSTRIP = W / SWF;    // 16 strips per image
constexpr int NBLK = B * NSTRIP;   // 512 one-wave blocks
constexpr int D = 32;              // prefetch depth in rows; MUST divide H
static_assert(H % D == 0, "D must divide H");

__global__ __launch_bounds__(64) void cummax_stream(const float* __restrict__ x,
                                                    float* __restrict__ o) {
    const int sid = blockIdx.x;
    const int b = sid >> 4;             // image
    const int st = sid & (NSTRIP - 1);  // strip within row
    const int lane = threadIdx.x;       // 0..63 = float column within strip

    const size_t base = (size_t)b * H * W + (size_t)st * SWF + lane;
    const float* xp = x + base;
    float* op = o + base;

    float carry = -__builtin_inff();
    float buf[D];

    // prologue: prefetch rows 0..D-1
#pragma unroll
    for (int r = 0; r < D; ++r) buf[r] = xp[(size_t)r * W];

    // main: process D rows, prefetch the next D (all buf indices static)
    int hb = 0;
    for (; hb < H - D; hb += D) {
        const float* xn = xp + (size_t)(hb + D) * W;
        float* on = op + (size_t)hb * W;
#pragma unroll
        for (int r = 0; r < D; ++r) {
            float v = buf[r];
            buf[r] = xn[(size_t)r * W];       // prefetch row hb+D+r
            carry = fmaxf(carry, v);
            on[(size_t)r * W] = carry;        // store row hb+r
        }
    }

    // epilogue: last D rows (already in buf), no prefetch
    {
        float* on = op + (size_t)hb * W;
#pragma unroll
        for (int r = 0; r < D; ++r) {
            carry = fmaxf(carry, buf[r]);
            on[(size_t)r * W] = carry;
        }
    }
}

extern "C" void kernel_launch(void* const* d_in, const int* in_sizes, int n_in,
                              void* d_out, int out_size, void* d_ws, size_t ws_size,
                              hipStream_t stream) {
    const float* x = (const float*)d_in[0];
    float* out = (float*)d_out;
    cummax_stream<<<NBLK, 64, 0, stream>>>(x, out);
}